// Round 2
// baseline (272.418 us; speedup 1.0000x reference)
//
#include <hip/hip_runtime.h>
#include <hip/hip_bf16.h>
#include <stdint.h>

// QuantizedLinear: out[16,11008] = x[16,4096] @ ((W - zp)*scale)^T
// HARNESS NOTE: integer inputs are materialized as int32 ("integer -> const
// int*"), so W is a 180 MB int32 buffer. Roofline = 180 MB / 6.3 TB/s ~ 29 us.
// Measured context: ~210 us of each iteration is harness fillBuffer resets
// (2 x 105 us @ 86% HBM peak) we cannot touch; our kernels are the ~47 us
// remainder. This version attacks qgemm's tail imbalance:
//   grid 688 (2.69 blk/CU, ceil 3 -> 11.6% tail waste + parallelism collapse)
//   -> K-split 4: grid 2752 (10.75 blk/CU, 2.3% waste), fp32 atomicAdd reduce.
// Output zeroing is folded into quant_x (no extra launch).

#define M_TOK 16
#define K_DIM 4096
#define N_OUT 11008

typedef int v4i __attribute__((ext_vector_type(4)));

// ---------------- Kernel 1: per-token quantization of x + zero(out) -------
// ws layout: xh[16*4096] | xl[16*4096] | s1[16] | sumx[16]
__global__ __launch_bounds__(256) void quant_x_kernel(
    const float* __restrict__ x, int8_t* __restrict__ xh,
    int8_t* __restrict__ xl, float* __restrict__ s1_out,
    float* __restrict__ sumx_out, float* __restrict__ out) {
  const int t = blockIdx.x;      // token
  const int tid = threadIdx.x;   // 256 threads, 16 consecutive elems each

  // Zero the output buffer (qgemm accumulates with atomicAdd).
  // 16*11008 floats = 44032 float4 across 16*256 = 4096 threads.
  {
    float4* o4 = (float4*)out;
    const int gidx = blockIdx.x * 256 + tid;
    const float4 z = {0.f, 0.f, 0.f, 0.f};
#pragma unroll
    for (int i = 0; i < 11; ++i) {
      int idx = gidx + i * 4096;
      if (idx < (M_TOK * N_OUT) / 4) o4[idx] = z;
    }
  }

  const float4* xv = (const float4*)(x + (long)t * K_DIM) + tid * 4;

  float vals[16];
  float m = 0.0f, s = 0.0f;
#pragma unroll
  for (int j = 0; j < 4; ++j) {
    float4 f = xv[j];
    vals[j * 4 + 0] = f.x; vals[j * 4 + 1] = f.y;
    vals[j * 4 + 2] = f.z; vals[j * 4 + 3] = f.w;
    m = fmaxf(m, fmaxf(fmaxf(fabsf(f.x), fabsf(f.y)),
                       fmaxf(fabsf(f.z), fabsf(f.w))));
    s += f.x + f.y + f.z + f.w;
  }
#pragma unroll
  for (int off = 32; off > 0; off >>= 1) {
    m = fmaxf(m, __shfl_xor(m, off));
    s += __shfl_xor(s, off);
  }
  __shared__ float lm[4], ls[4];
  const int w = tid >> 6;
  if ((tid & 63) == 0) { lm[w] = m; ls[w] = s; }
  __syncthreads();
  m = fmaxf(fmaxf(lm[0], lm[1]), fmaxf(lm[2], lm[3]));
  s = ls[0] + ls[1] + ls[2] + ls[3];

  const float s1 = (m > 0.0f) ? (m * (1.0f / 127.0f)) : 1.0f;
  const float inv = 1.0f / s1;
  if (tid == 0) { s1_out[t] = s1; sumx_out[t] = s; }

  int hq[16], lq[16];
#pragma unroll
  for (int j = 0; j < 16; ++j) {
    float xf = vals[j];
    float h = rintf(xf * inv);
    h = fminf(fmaxf(h, -127.0f), 127.0f);
    float resid = xf - h * s1;
    float l = rintf(resid * inv * 256.0f);
    l = fminf(fmaxf(l, -128.0f), 127.0f);
    hq[j] = (int)h;
    lq[j] = (int)l;
  }
  int4 hv, lv;
  int* hp = (int*)&hv;
  int* lp = (int*)&lv;
#pragma unroll
  for (int d = 0; d < 4; ++d) {
    uint32_t hw = 0, lw = 0;
#pragma unroll
    for (int j = 0; j < 4; ++j) {
      hw |= (uint32_t)(hq[d * 4 + j] & 0xff) << (8 * j);
      lw |= (uint32_t)(lq[d * 4 + j] & 0xff) << (8 * j);
    }
    hp[d] = (int)hw;
    lp[d] = (int)lw;
  }
  ((int4*)xh)[(long)t * 256 + tid] = hv;
  ((int4*)xl)[(long)t * 256 + tid] = lv;
}

// ---------------- Kernel 2: weight-streaming i8 MFMA GEMM (K-split 4) -----
// Grid = (N_OUT/16) * 4 blocks. Block b: output tile (b>>2)*16, K slice
// (b&3)*1024. 4 waves/block, wave w owns K range [kidx*1024 + w*256, +256).
// Per 64-k chunk a lane loads 16 int32 weights (64 B contiguous, four
// nontemporal dwordx4), packs low bytes into the 16-int8 B fragment. A hi/lo
// fragments come from the L2-resident x planes. LDS reduces the 4 waves,
// then one fp32 atomicAdd per (token, col) folds the 4 K-split partials.
__global__ __launch_bounds__(256) void qgemm_kernel(
    const int* __restrict__ W, const int8_t* __restrict__ xh,
    const int8_t* __restrict__ xl, const float* __restrict__ s1,
    const float* __restrict__ sumx, const float* __restrict__ scale_p,
    const int* __restrict__ zp_p, float* __restrict__ out) {
  const int tid = threadIdx.x;
  const int lane = tid & 63;
  const int w = tid >> 6;              // wave id = K sub-split within block
  const int kidx = blockIdx.x & 3;     // K split id (1024 each)
  const int obase = (blockIdx.x >> 2) * 16;
  const int n = lane & 15;             // output-row (B col) / token (A row)
  const int g = lane >> 4;             // k sub-group within 64-k chunk
  const long kbase = (long)kidx * 1024 + w * 256 + g * 16;

  const int* Wp = W + (long)(obase + n) * K_DIM + kbase;  // int32 elements
  const v4i* Ah = (const v4i*)(xh + (long)n * K_DIM + kbase);
  const v4i* Al = (const v4i*)(xl + (long)n * K_DIM + kbase);

  v4i accH = {0, 0, 0, 0};
  v4i accL = {0, 0, 0, 0};
#pragma unroll
  for (int c = 0; c < 4; ++c) {        // 4 chunks x 64 k = 256
    const v4i* wq = (const v4i*)(Wp + c * 64);
    v4i b;
#pragma unroll
    for (int d = 0; d < 4; ++d) {
      v4i q = __builtin_nontemporal_load(wq + d);
      uint32_t packed = ((uint32_t)q.x & 0xffu) |
                        (((uint32_t)q.y & 0xffu) << 8) |
                        (((uint32_t)q.z & 0xffu) << 16) |
                        (((uint32_t)q.w & 0xffu) << 24);
      b[d] = (int)packed;
    }
    v4i ah = Ah[c * 4];
    v4i al = Al[c * 4];
    accH = __builtin_amdgcn_mfma_i32_16x16x64_i8(ah, b, accH, 0, 0, 0);
    accL = __builtin_amdgcn_mfma_i32_16x16x64_i8(al, b, accL, 0, 0, 0);
  }

  // C layout (16x16): col = lane&15 (=o), row = (lane>>4)*4 + reg (=token)
  __shared__ float red[4][16 * 17];
#pragma unroll
  for (int r = 0; r < 4; ++r) {
    float f = (float)accH[r] + (float)accL[r] * (1.0f / 256.0f);
    int t = g * 4 + r;
    red[w][t * 17 + n] = f;
  }
  __syncthreads();

  const int t = tid >> 4;
  const int col = tid & 15;
  float sum = red[0][t * 17 + col] + red[1][t * 17 + col] +
              red[2][t * 17 + col] + red[3][t * 17 + col];
  const float sc = scale_p[0];
  float o = sc * (s1[t] * sum);
  if (kidx == 0) {
    const float zp = (float)zp_p[0];
    o -= sc * zp * sumx[t];
  }
  atomicAdd(&out[(long)t * N_OUT + obase + col], o);
}

extern "C" void kernel_launch(void* const* d_in, const int* in_sizes, int n_in,
                              void* d_out, int out_size, void* d_ws,
                              size_t ws_size, hipStream_t stream) {
  const float* x = (const float*)d_in[0];
  const int* Wq = (const int*)d_in[1];          // int inputs come as int32
  const float* scale_p = (const float*)d_in[2];
  const int* zp_p = (const int*)d_in[3];
  float* out = (float*)d_out;

  int8_t* xh = (int8_t*)d_ws;
  int8_t* xl = xh + (long)M_TOK * K_DIM;
  float* s1 = (float*)(xl + (long)M_TOK * K_DIM);
  float* sumx = s1 + M_TOK;

  quant_x_kernel<<<M_TOK, 256, 0, stream>>>(x, xh, xl, s1, sumx, out);
  qgemm_kernel<<<(N_OUT / 16) * 4, 256, 0, stream>>>(Wq, xh, xl, s1, sumx,
                                                     scale_p, zp_p, out);
}

// Round 3
// 254.047 us; speedup vs baseline: 1.0723x; 1.0723x over previous
//
#include <hip/hip_runtime.h>
#include <hip/hip_bf16.h>
#include <stdint.h>

// QuantizedLinear: out[16,11008] = x[16,4096] @ ((W - zp)*scale)^T
// HARNESS NOTE: integer inputs are materialized as int32, so W is a 180 MB
// int32 buffer. Roofline = 180 MB / 6.3 TB/s ~ 29 us. ~215 us of each
// iteration is harness fillBuffer resets we cannot touch.
//
// R2 post-mortem: K-split+atomics+NT regressed (46->57 us our-portion).
// All 688 blocks are co-resident (4.4KB LDS, 4 waves) -> no launch tail.
// R0's 68%-of-BW gap attributed to DRAM row thrash: i8 MFMA B-frag layout
// makes every wave-instr touch 16 rows x 256 B granules (11k interleaved
// streams -> row-activate bound).
//
// R3: reg-stage W through a packed LDS tile. Per 256-k chunk each wave
// loads 4 rows as 1 KB CONTIGUOUS per instruction (lane*16B dwordx4),
// packs int32->int8 in-register, ds_write_b32 (XOR-swizzled). B-frag is
// then ONE ds_read_b128. Double-buffered, static-indexed prefetch,
// one barrier per chunk. No atomics, direct store epilogue.

#define M_TOK 16
#define K_DIM 4096
#define N_OUT 11008

typedef int v4i __attribute__((ext_vector_type(4)));

// ---------------- Kernel 1: per-token quantization of x ----------------
// ws layout: xh[16*4096] | xl[16*4096] | s1[16] | sumx[16]
__global__ __launch_bounds__(256) void quant_x_kernel(
    const float* __restrict__ x, int8_t* __restrict__ xh,
    int8_t* __restrict__ xl, float* __restrict__ s1_out,
    float* __restrict__ sumx_out) {
  const int t = blockIdx.x;      // token
  const int tid = threadIdx.x;   // 256 threads, 16 consecutive elems each
  const float4* xv = (const float4*)(x + (long)t * K_DIM) + tid * 4;

  float vals[16];
  float m = 0.0f, s = 0.0f;
#pragma unroll
  for (int j = 0; j < 4; ++j) {
    float4 f = xv[j];
    vals[j * 4 + 0] = f.x; vals[j * 4 + 1] = f.y;
    vals[j * 4 + 2] = f.z; vals[j * 4 + 3] = f.w;
    m = fmaxf(m, fmaxf(fmaxf(fabsf(f.x), fabsf(f.y)),
                       fmaxf(fabsf(f.z), fabsf(f.w))));
    s += f.x + f.y + f.z + f.w;
  }
#pragma unroll
  for (int off = 32; off > 0; off >>= 1) {
    m = fmaxf(m, __shfl_xor(m, off));
    s += __shfl_xor(s, off);
  }
  __shared__ float lm[4], ls[4];
  const int w = tid >> 6;
  if ((tid & 63) == 0) { lm[w] = m; ls[w] = s; }
  __syncthreads();
  m = fmaxf(fmaxf(lm[0], lm[1]), fmaxf(lm[2], lm[3]));
  s = ls[0] + ls[1] + ls[2] + ls[3];

  const float s1 = (m > 0.0f) ? (m * (1.0f / 127.0f)) : 1.0f;
  const float inv = 1.0f / s1;
  if (tid == 0) { s1_out[t] = s1; sumx_out[t] = s; }

  int hq[16], lq[16];
#pragma unroll
  for (int j = 0; j < 16; ++j) {
    float xf = vals[j];
    float h = rintf(xf * inv);
    h = fminf(fmaxf(h, -127.0f), 127.0f);
    float resid = xf - h * s1;
    float l = rintf(resid * inv * 256.0f);
    l = fminf(fmaxf(l, -128.0f), 127.0f);
    hq[j] = (int)h;
    lq[j] = (int)l;
  }
  int4 hv, lv;
  int* hp = (int*)&hv;
  int* lp = (int*)&lv;
#pragma unroll
  for (int d = 0; d < 4; ++d) {
    uint32_t hw = 0, lw = 0;
#pragma unroll
    for (int j = 0; j < 4; ++j) {
      hw |= (uint32_t)(hq[d * 4 + j] & 0xff) << (8 * j);
      lw |= (uint32_t)(lq[d * 4 + j] & 0xff) << (8 * j);
    }
    hp[d] = (int)hw;
    lp[d] = (int)lw;
  }
  ((int4*)xh)[(long)t * 256 + tid] = hv;
  ((int4*)xl)[(long)t * 256 + tid] = lv;
}

// ---------------- Kernel 2: LDS-staged weight-streaming i8 MFMA GEMM ------
// Grid = 688 blocks x 256 thr (4 waves). Block owns 16 output rows, full K.
// Per 256-k chunk: wave w stages rows 4w..4w+3 (1 KB contiguous per row per
// instruction), packs to int8, writes swizzled LDS; each wave then computes
// its K-quarter of the chunk with one ds_read_b128 + hi/lo MFMA pair.
// 16 chunks, double-buffered 2x4KB LDS, one barrier per chunk.
__global__ __launch_bounds__(256) void qgemm_kernel(
    const int* __restrict__ W, const int8_t* __restrict__ xh,
    const int8_t* __restrict__ xl, const float* __restrict__ s1,
    const float* __restrict__ sumx, const float* __restrict__ scale_p,
    const int* __restrict__ zp_p, float* __restrict__ out) {
  const int tid = threadIdx.x;
  const int lane = tid & 63;
  const int w = tid >> 6;          // wave id = K quarter within chunk
  const int obase = blockIdx.x * 16;
  const int n = lane & 15;         // output-row (B col) / token (A row)
  const int g = lane >> 4;         // k sub-group within 64-k window
  const int r0 = w * 4;            // first staged row for this wave

  __shared__ v4i wbuf[2][256];     // [buf][row*16 + slot] packed int8
  __shared__ float red[4][16 * 17];

  // Staging pointers: 1 KB contiguous per row per chunk, lane*16B apart.
  const v4i* Wr0 = (const v4i*)(W + (long)(obase + r0 + 0) * K_DIM) + lane;
  const v4i* Wr1 = (const v4i*)(W + (long)(obase + r0 + 1) * K_DIM) + lane;
  const v4i* Wr2 = (const v4i*)(W + (long)(obase + r0 + 2) * K_DIM) + lane;
  const v4i* Wr3 = (const v4i*)(W + (long)(obase + r0 + 3) * K_DIM) + lane;

  // LDS write index (dword units), XOR-swizzled within each 256B row so the
  // b128 fragment reads spread across all 8 bank-rows (write side is a lane
  // permutation -> 2 lanes/bank = free).
  int wr_idx[4];
#pragma unroll
  for (int r = 0; r < 4; ++r) {
    const int row = r0 + r;
    wr_idx[r] = row * 64 + (lane ^ ((row & 7) << 2));
  }
  // LDS read index (v4i units): logical slot 4w+g of row n, swizzled.
  const int rd_idx = n * 16 + ((4 * w + g) ^ (n & 7));

  // A fragments (L2-resident x planes): 16B per chunk per plane.
  const v4i* Ah = (const v4i*)xh + (n * 256 + w * 4 + g);
  const v4i* Al = (const v4i*)xl + (n * 256 + w * 4 + g);

  // Prologue: fetch chunk 0 into register set 0.
  v4i wreg[2][4];
  wreg[0][0] = Wr0[0];
  wreg[0][1] = Wr1[0];
  wreg[0][2] = Wr2[0];
  wreg[0][3] = Wr3[0];

  v4i accH = {0, 0, 0, 0};
  v4i accL = {0, 0, 0, 0};

#pragma unroll
  for (int c = 0; c < 16; ++c) {
    const int cur = c & 1;
    if (c + 1 < 16) {            // issue next-chunk loads (static index)
      const int nxt = (c + 1) & 1;
      wreg[nxt][0] = Wr0[(c + 1) * 64];
      wreg[nxt][1] = Wr1[(c + 1) * 64];
      wreg[nxt][2] = Wr2[(c + 1) * 64];
      wreg[nxt][3] = Wr3[(c + 1) * 64];
    }
    // Pack current chunk (low byte of each int32) and write swizzled LDS.
    uint32_t* wb = (uint32_t*)wbuf[cur];
#pragma unroll
    for (int r = 0; r < 4; ++r) {
      v4i q = wreg[cur][r];
      uint32_t packed = ((uint32_t)q.x & 0xffu) |
                        (((uint32_t)q.y & 0xffu) << 8) |
                        (((uint32_t)q.z & 0xffu) << 16) |
                        (((uint32_t)q.w & 0xffu) << 24);
      wb[wr_idx[r]] = packed;
    }
    __syncthreads();
    const v4i b = wbuf[cur][rd_idx];
    accH = __builtin_amdgcn_mfma_i32_16x16x64_i8(Ah[c * 16], b, accH, 0, 0, 0);
    accL = __builtin_amdgcn_mfma_i32_16x16x64_i8(Al[c * 16], b, accL, 0, 0, 0);
  }

  // C layout (16x16): col = lane&15 (=o), row = (lane>>4)*4 + reg (=token)
#pragma unroll
  for (int r = 0; r < 4; ++r) {
    float f = (float)accH[r] + (float)accL[r] * (1.0f / 256.0f);
    const int t = g * 4 + r;
    red[w][t * 17 + n] = f;
  }
  __syncthreads();

  const int t = tid >> 4;
  const int col = tid & 15;
  const float sum = red[0][t * 17 + col] + red[1][t * 17 + col] +
                    red[2][t * 17 + col] + red[3][t * 17 + col];
  const float sc = scale_p[0];
  const float zp = (float)zp_p[0];
  const float o = sc * (s1[t] * sum) - sc * zp * sumx[t];
  out[(long)t * N_OUT + obase + col] = o;
}

extern "C" void kernel_launch(void* const* d_in, const int* in_sizes, int n_in,
                              void* d_out, int out_size, void* d_ws,
                              size_t ws_size, hipStream_t stream) {
  const float* x = (const float*)d_in[0];
  const int* Wq = (const int*)d_in[1];          // int inputs come as int32
  const float* scale_p = (const float*)d_in[2];
  const int* zp_p = (const int*)d_in[3];
  float* out = (float*)d_out;

  int8_t* xh = (int8_t*)d_ws;
  int8_t* xl = xh + (long)M_TOK * K_DIM;
  float* s1 = (float*)(xl + (long)M_TOK * K_DIM);
  float* sumx = s1 + M_TOK;

  quant_x_kernel<<<M_TOK, 256, 0, stream>>>(x, xh, xl, s1, sumx);
  qgemm_kernel<<<N_OUT / 16, 256, 0, stream>>>(Wq, xh, xl, s1, sumx, scale_p,
                                               zp_p, out);
}